// Round 12
// baseline (276.954 us; speedup 1.0000x reference)
//
#include <hip/hip_runtime.h>
#include <hip/hip_cooperative_groups.h>

namespace cg = cooperative_groups;

// Problem constants (reference: B=8, N=8192, D=64, NNZ=2097152)
#define NB 8
#define NN 8192
#define ND 64

// Binning geometry: 512 buckets x 128 output rows; 16 sub-buckets each.
// Round-11 lesson: bin was bound by ~256 serialized atomics/counter; SUB=16
// cuts the per-counter chain to ~64 (mean), SUBCAP=128 = mean+8sigma.
// Counters stay padded to one per 64B line (round-6 lesson).
#define NBKT 512
#define ROWS_PER_BKT 128
#define SUB 16
#define NSLOT (NBKT * SUB)       // 8192
#define SUBCAP 128
#define BKT_CAP (SUB * SUBCAP)   // 2048 entries max per bucket
#define CNT_STRIDE 16            // 64B per counter
#define SPILLCAP 16384
#define FUSED_BLOCKS 512
#define FUSED_THREADS 1024

// Mask format detection (bool upload convention unknown: 1-byte vs int32).
// Wave-parallel: any of the first 256 words of X_mask > 1 => byte bools.
__device__ __forceinline__ bool detect_bytes_block(const void* xm_raw,
                                                   int* s_flag) {
    if (threadIdx.x == 0) *s_flag = 0;
    __syncthreads();
    const unsigned int* w = (const unsigned int*)xm_raw;
    if (threadIdx.x < 256 && w[threadIdx.x] > 1u) atomicOr(s_flag, 1);
    __syncthreads();
    return *s_flag != 0;
}

__device__ __forceinline__ unsigned int mask_at(const void* m, bool bytes, int i) {
    return bytes ? (unsigned int)((const unsigned char*)m)[i]
                 : ((const unsigned int*)m)[i];
}

// ---------------------------------------------------------------------------
// Fused cooperative kernel: zero-counters | bin | accum with grid.sync()
// between phases. 512 blocks x 1024 threads = exactly 2 blocks/CU resident.
// ---------------------------------------------------------------------------
__global__ __launch_bounds__(FUSED_THREADS, 8) void fused_kernel(
    const int* __restrict__ Ab, const int* __restrict__ Ar,
    const int* __restrict__ Ac, const float* __restrict__ Av,
    const float* __restrict__ X,
    const void* __restrict__ Xm_raw, const void* __restrict__ Tm_raw,
    unsigned int* __restrict__ cnt, int2* __restrict__ buckets,
    unsigned int* __restrict__ spill_cnt, int2* __restrict__ spill,
    float* __restrict__ out, int nq) {

    __shared__ int s_flag;
    __shared__ int2 sorted[BKT_CAP];                 // 16 KB
    __shared__ unsigned int hist[ROWS_PER_BKT];
    __shared__ unsigned int rowstart[ROWS_PER_BKT + 1];
    __shared__ unsigned int cursor[ROWS_PER_BKT];
    __shared__ unsigned int s_n[SUB];
    __shared__ unsigned int s_nsp;

    const bool bytes = detect_bytes_block(Xm_raw, &s_flag);
    const int t    = threadIdx.x;
    const int gtid = blockIdx.x * FUSED_THREADS + t;

    // ---- phase 0: zero padded counters + spill counter ----
    if (gtid < NSLOT * CNT_STRIDE) cnt[gtid] = 0u;
    if (gtid == 0) *spill_cnt = 0u;
    cg::this_grid().sync();

    // ---- phase 1: bin surviving edges into sub-buckets ----
    {
        const int sub = blockIdx.x & (SUB - 1);
        const int4*   Ab4 = (const int4*)Ab;
        const int4*   Ar4 = (const int4*)Ar;
        const int4*   Ac4 = (const int4*)Ac;
        const float4* Av4 = (const float4*)Av;
        const int str = gridDim.x * blockDim.x;
        for (int i = gtid; i < nq; i += str) {
            const int4   b4 = Ab4[i];
            const int4   r4 = Ar4[i];
            const int4   c4 = Ac4[i];
            const float4 v4 = Av4[i];
            const int   bs[4] = {b4.x, b4.y, b4.z, b4.w};
            const int   rs[4] = {r4.x, r4.y, r4.z, r4.w};
            const int   cs[4] = {c4.x, c4.y, c4.z, c4.w};
            const float vs[4] = {v4.x, v4.y, v4.z, v4.w};
            #pragma unroll
            for (int j = 0; j < 4; ++j) {
                const int seg  = bs[j] * NN + rs[j];
                const int xrow = bs[j] * NN + cs[j];
                if (mask_at(Tm_raw, bytes, seg) && mask_at(Xm_raw, bytes, xrow)) {
                    const int slot = (seg >> 7) * SUB + sub;
                    const unsigned int pos = atomicAdd(&cnt[slot * CNT_STRIDE], 1u);
                    if (pos < SUBCAP) {
                        buckets[(size_t)slot * SUBCAP + pos] =
                            make_int2(xrow | ((seg & (ROWS_PER_BKT - 1)) << 16),
                                      __float_as_int(vs[j]));
                    } else {
                        const unsigned int sp = atomicAdd(spill_cnt, 1u);
                        if (sp < SPILLCAP)
                            spill[sp] = make_int2(xrow | (seg << 16),
                                                  __float_as_int(vs[j]));
                    }
                }
            }
        }
    }
    cg::this_grid().sync();

    // ---- phase 2: accumulate one bucket per block ----
    const int bkt = blockIdx.x;

    if (t < ROWS_PER_BKT) hist[t] = 0;
    if (t < SUB) s_n[t] = min(cnt[(bkt * SUB + t) * CNT_STRIDE], (unsigned int)SUBCAP);
    if (t == 0) s_nsp = min(*spill_cnt, (unsigned int)SPILLCAP);
    __syncthreads();

    // a+b) stage + histogram (idx space: sub = idx/SUBCAP, off = idx%SUBCAP)
    int2 e0s, e1s;
    int r0 = -1, r1 = -1;
    {
        int idx = t, sub = idx >> 7, off = idx & (SUBCAP - 1);
        if ((unsigned int)off < s_n[sub]) {
            e0s = buckets[(size_t)(bkt * SUB + sub) * SUBCAP + off];
            r0 = (e0s.x >> 16) & (ROWS_PER_BKT - 1);
            atomicAdd(&hist[r0], 1u);
        }
        idx = t + FUSED_THREADS; sub = idx >> 7; off = idx & (SUBCAP - 1);
        if ((unsigned int)off < s_n[sub]) {
            e1s = buckets[(size_t)(bkt * SUB + sub) * SUBCAP + off];
            r1 = (e1s.x >> 16) & (ROWS_PER_BKT - 1);
            atomicAdd(&hist[r1], 1u);
        }
    }
    __syncthreads();

    // c) exclusive scan of 128 counts by wave 0
    if (t < 64) {
        const unsigned int h0 = hist[t], h1 = hist[64 + t];
        unsigned int a = h0, b = h1;
        for (int off = 1; off < 64; off <<= 1) {
            unsigned int v = __shfl_up(a, off);
            if (t >= off) a += v;
        }
        const unsigned int atot = __shfl(a, 63);
        for (int off = 1; off < 64; off <<= 1) {
            unsigned int v = __shfl_up(b, off);
            if (t >= off) b += v;
        }
        rowstart[t]      = a - h0;
        rowstart[64 + t] = atot + b - h1;
        cursor[t]        = a - h0;
        cursor[64 + t]   = atot + b - h1;
        if (t == 63) rowstart[128] = atot + b;
    }
    __syncthreads();

    // d) counting-sort into LDS
    if (r0 >= 0) { const unsigned int p = atomicAdd(&cursor[r0], 1u); sorted[p] = e0s; }
    if (r1 >= 0) { const unsigned int p = atomicAdd(&cursor[r1], 1u); sorted[p] = e1s; }
    __syncthreads();

    // e) register accumulation: wave w owns rows 8w..8w+7, lane == d,
    //    unroll-4 for 4 outstanding X gathers
    const int wave = t >> 6;
    const int lane = t & 63;
    const int rbase = wave * 8;
    float acc[8];
    #pragma unroll
    for (int j = 0; j < 8; ++j) {
        unsigned int k = rowstart[rbase + j];
        const unsigned int ke = rowstart[rbase + j + 1];
        float a = 0.f;
        for (; k + 4 <= ke; k += 4) {
            const int2 e0 = sorted[k],     e1 = sorted[k + 1];
            const int2 e2 = sorted[k + 2], e3 = sorted[k + 3];
            const float x0 = X[((size_t)(e0.x & 0xFFFF) << 6) + lane];
            const float x1 = X[((size_t)(e1.x & 0xFFFF) << 6) + lane];
            const float x2 = X[((size_t)(e2.x & 0xFFFF) << 6) + lane];
            const float x3 = X[((size_t)(e3.x & 0xFFFF) << 6) + lane];
            a = fmaf(__int_as_float(e0.y), x0, a);
            a = fmaf(__int_as_float(e1.y), x1, a);
            a = fmaf(__int_as_float(e2.y), x2, a);
            a = fmaf(__int_as_float(e3.y), x3, a);
        }
        for (; k < ke; ++k) {
            const int2 e = sorted[k];
            a = fmaf(__int_as_float(e.y), X[((size_t)(e.x & 0xFFFF) << 6) + lane], a);
        }
        acc[j] = a;
    }

    // fold spill entries (expected none); static acc indexing (rule #20)
    if (s_nsp) {
        const int seglo = bkt * ROWS_PER_BKT;
        for (unsigned int k = 0; k < s_nsp; ++k) {
            const int2 e = spill[k];
            const int r = ((e.x >> 16) & 0xFFFF) - seglo;
            if (r >= rbase && r < rbase + 8) {
                const float xv = X[((size_t)(e.x & 0xFFFF) << 6) + lane];
                const float vv = __int_as_float(e.y);
                #pragma unroll
                for (int j = 0; j < 8; ++j)
                    if (r == rbase + j) acc[j] = fmaf(vv, xv, acc[j]);
            }
        }
    }

    float* obase = out + ((size_t)bkt * ROWS_PER_BKT + rbase) * ND + lane;
    #pragma unroll
    for (int j = 0; j < 8; ++j) obase[(size_t)j * ND] = acc[j];
}

// ---------------------------------------------------------------------------
// Fallback: proven atomic scatter (unexpected shape or small ws), raw masks.
// ---------------------------------------------------------------------------
__global__ void coo_scatter_kernel(const int* __restrict__ Ab,
                                   const int* __restrict__ Ar,
                                   const int* __restrict__ Ac,
                                   const float* __restrict__ Av,
                                   const float* __restrict__ X,
                                   const void* __restrict__ Xm_raw,
                                   const void* __restrict__ Tm_raw,
                                   float* __restrict__ out, int nnz) {
    __shared__ int s_flag;
    const bool bytes = detect_bytes_block(Xm_raw, &s_flag);
    const int groups_per_block = blockDim.x >> 6;
    const int g0 = blockIdx.x * groups_per_block + (threadIdx.x >> 6);
    const int gstr = gridDim.x * groups_per_block;
    const int lane = threadIdx.x & 63;
    for (int e = g0; e < nnz; e += gstr) {
        const int b = Ab[e];
        const int r = Ar[e];
        if (!mask_at(Tm_raw, bytes, b * NN + r)) continue;
        const int c = Ac[e];
        if (!mask_at(Xm_raw, bytes, b * NN + c)) continue;
        const float v = Av[e];
        const float x = X[((size_t)(b * NN + c)) * ND + lane];
        atomicAdd(&out[((size_t)(b * NN + r)) * ND + lane], v * x);
    }
}

extern "C" void kernel_launch(void* const* d_in, const int* in_sizes, int n_in,
                              void* d_out, int out_size, void* d_ws, size_t ws_size,
                              hipStream_t stream) {
    const int*   Ab = (const int*)d_in[0];
    const int*   Ar = (const int*)d_in[1];
    const int*   Ac = (const int*)d_in[2];
    const float* Av = (const float*)d_in[3];
    const float* X  = (const float*)d_in[4];
    const void*  Xm_raw = d_in[5];
    const void*  Tm_raw = d_in[6];
    float* out = (float*)d_out;

    const int nnz   = in_sizes[0];
    const int nmask = in_sizes[5];   // B*N

    // Workspace layout (8B aligned): ~8.7 MB total
    unsigned char* w = (unsigned char*)d_ws;
    unsigned int* cnt       = (unsigned int*)w;  w += (size_t)NSLOT * CNT_STRIDE * 4;
    unsigned int* spill_cnt = (unsigned int*)w;  w += 16;
    int2*         buckets   = (int2*)w;          w += (size_t)NSLOT * SUBCAP * 8;
    int2*         spill     = (int2*)w;          w += (size_t)SPILLCAP * 8;
    const size_t needed = (size_t)(w - (unsigned char*)d_ws);

    // Fast path requires the known problem shape (16-bit xrow/seg packing,
    // sub-bucket capacity sized for nnz=2M at ~25% survival, and
    // nq <= FUSED_BLOCKS*FUSED_THREADS so the bin phase covers all edges).
    const int nq = nnz >> 2;
    if (ws_size < needed || nmask != NBKT * ROWS_PER_BKT || (nnz & 3) ||
        nq > FUSED_BLOCKS * FUSED_THREADS) {
        hipMemsetAsync(d_out, 0, (size_t)out_size * sizeof(float), stream);
        coo_scatter_kernel<<<16384, 256, 0, stream>>>(Ab, Ar, Ac, Av, X,
                                                      Xm_raw, Tm_raw, out, nnz);
        return;
    }

    // Single cooperative dispatch: zero | grid.sync | bin | grid.sync | accum.
    // No memset dispatch (phase 0 zeroes cnt), no out memset (accum writes
    // every output row).
    void* kargs[] = {
        (void*)&Ab, (void*)&Ar, (void*)&Ac, (void*)&Av, (void*)&X,
        (void*)&Xm_raw, (void*)&Tm_raw,
        (void*)&cnt, (void*)&buckets, (void*)&spill_cnt, (void*)&spill,
        (void*)&out, (void*)&nq
    };
    hipLaunchCooperativeKernel((const void*)fused_kernel,
                               dim3(FUSED_BLOCKS), dim3(FUSED_THREADS),
                               kargs, 0, stream);
}

// Round 14
// 149.889 us; speedup vs baseline: 1.8477x; 1.8477x over previous
//
#include <hip/hip_runtime.h>

// Problem constants (reference: B=8, N=8192, D=64, NNZ=2097152)
#define NB 8
#define NN 8192
#define ND 64

// Binning geometry: 512 buckets x 128 output rows; 16 sub-buckets each.
// Round-11 arithmetic: bin was bound by ~256 serialized atomics/counter
// (~32us); SUB=16 cuts the chain to ~64. Counters stay padded to one per
// 64B line (round-6 lesson: line-sharing was a 4x serialization).
// Round-12 lesson: do NOT fuse via grid.sync -- cooperative barrier cost
// ~90us on 8 XCDs, far more than the ~20us of launch boundaries it saved.
#define NBKT 512
#define ROWS_PER_BKT 128
#define SUB 16
#define NSLOT (NBKT * SUB)       // 8192
#define SUBCAP 128
#define BKT_CAP (SUB * SUBCAP)   // 2048 entries max per bucket
#define CNT_STRIDE 16            // 64B per counter
#define SPILLCAP 16384

// Mask format detection (bool upload convention unknown: 1-byte vs int32).
// Wave-parallel: any of the first 256 words of X_mask > 1 => byte bools.
__device__ __forceinline__ bool detect_bytes_block(const void* xm_raw,
                                                   int* s_flag) {
    if (threadIdx.x == 0) *s_flag = 0;
    __syncthreads();
    const unsigned int* w = (const unsigned int*)xm_raw;
    if (threadIdx.x < 256 && w[threadIdx.x] > 1u) atomicOr(s_flag, 1);
    __syncthreads();
    return *s_flag != 0;
}

__device__ __forceinline__ unsigned int mask_at(const void* m, bool bytes, int i) {
    return bytes ? (unsigned int)((const unsigned char*)m)[i]
                 : ((const unsigned int*)m)[i];
}

// ---------------------------------------------------------------------------
// Pass 1: bin surviving edges into sub-buckets. int4-vectorized index reads,
// raw-mask lookups (L2-hot). Entry = (xrow | row_in_bucket<<16, val_bits).
// ---------------------------------------------------------------------------
__global__ void bin_kernel(const int* __restrict__ Ab, const int* __restrict__ Ar,
                           const int* __restrict__ Ac, const float* __restrict__ Av,
                           const void* __restrict__ Xm_raw,
                           const void* __restrict__ Tm_raw,
                           unsigned int* __restrict__ cnt,
                           int2* __restrict__ buckets,
                           unsigned int* __restrict__ spill_cnt,
                           int2* __restrict__ spill,
                           int nq) {
    __shared__ int s_flag;
    const bool bytes = detect_bytes_block(Xm_raw, &s_flag);

    const int sub = blockIdx.x & (SUB - 1);
    const int4*   Ab4 = (const int4*)Ab;
    const int4*   Ar4 = (const int4*)Ar;
    const int4*   Ac4 = (const int4*)Ac;
    const float4* Av4 = (const float4*)Av;
    int i = blockIdx.x * blockDim.x + threadIdx.x;
    const int str = gridDim.x * blockDim.x;
    for (; i < nq; i += str) {
        const int4   b4 = Ab4[i];
        const int4   r4 = Ar4[i];
        const int4   c4 = Ac4[i];
        const float4 v4 = Av4[i];
        const int   bs[4] = {b4.x, b4.y, b4.z, b4.w};
        const int   rs[4] = {r4.x, r4.y, r4.z, r4.w};
        const int   cs[4] = {c4.x, c4.y, c4.z, c4.w};
        const float vs[4] = {v4.x, v4.y, v4.z, v4.w};
        #pragma unroll
        for (int j = 0; j < 4; ++j) {
            const int seg  = bs[j] * NN + rs[j];
            const int xrow = bs[j] * NN + cs[j];
            if (mask_at(Tm_raw, bytes, seg) && mask_at(Xm_raw, bytes, xrow)) {
                const int slot = (seg >> 7) * SUB + sub;
                const unsigned int pos = atomicAdd(&cnt[slot * CNT_STRIDE], 1u);
                if (pos < SUBCAP) {
                    buckets[(size_t)slot * SUBCAP + pos] =
                        make_int2(xrow | ((seg & (ROWS_PER_BKT - 1)) << 16),
                                  __float_as_int(vs[j]));
                } else {
                    const unsigned int sp = atomicAdd(spill_cnt, 1u);
                    if (sp < SPILLCAP)
                        spill[sp] = make_int2(xrow | (seg << 16), __float_as_int(vs[j]));
                }
            }
        }
    }
}

// ---------------------------------------------------------------------------
// Pass 2: one block (1024 thr) per bucket.
//   a) stage <=2048 entries  b) LDS u32 histogram by row  c) wave-0 shfl scan
//   d) counting-sort into LDS  e) wave w accumulates rows 8w..8w+7 in VGPRs,
//      unroll-4 for 4 outstanding X gathers, folds spill entries (expected 0),
//      writes 8 coalesced 256B rows. Writes every row -> no out memset.
// ---------------------------------------------------------------------------
__global__ __launch_bounds__(1024) void accum_kernel(const unsigned int* __restrict__ cnt,
                                                     const int2* __restrict__ buckets,
                                                     const float* __restrict__ X,
                                                     const unsigned int* __restrict__ spill_cnt,
                                                     const int2* __restrict__ spill,
                                                     float* __restrict__ out) {
    __shared__ int2 sorted[BKT_CAP];                   // 16 KB
    __shared__ unsigned int hist[ROWS_PER_BKT];
    __shared__ unsigned int rowstart[ROWS_PER_BKT + 1];
    __shared__ unsigned int cursor[ROWS_PER_BKT];
    __shared__ unsigned int s_n[SUB];
    __shared__ unsigned int s_nsp;

    const int bkt = blockIdx.x;
    const int t = threadIdx.x;

    if (t < ROWS_PER_BKT) hist[t] = 0;
    if (t < SUB) s_n[t] = min(cnt[(bkt * SUB + t) * CNT_STRIDE], (unsigned int)SUBCAP);
    if (t == 0) s_nsp = min(*spill_cnt, (unsigned int)SPILLCAP);
    __syncthreads();

    // a+b) stage + histogram (idx space: sub = idx/SUBCAP, off = idx%SUBCAP)
    int2 e0s, e1s;
    int r0 = -1, r1 = -1;
    {
        int idx = t, sub = idx >> 7, off = idx & (SUBCAP - 1);
        if ((unsigned int)off < s_n[sub]) {
            e0s = buckets[(size_t)(bkt * SUB + sub) * SUBCAP + off];
            r0 = (e0s.x >> 16) & (ROWS_PER_BKT - 1);
            atomicAdd(&hist[r0], 1u);
        }
        idx = t + 1024; sub = idx >> 7; off = idx & (SUBCAP - 1);
        if ((unsigned int)off < s_n[sub]) {
            e1s = buckets[(size_t)(bkt * SUB + sub) * SUBCAP + off];
            r1 = (e1s.x >> 16) & (ROWS_PER_BKT - 1);
            atomicAdd(&hist[r1], 1u);
        }
    }
    __syncthreads();

    // c) exclusive scan of 128 counts by wave 0
    if (t < 64) {
        const unsigned int h0 = hist[t], h1 = hist[64 + t];
        unsigned int a = h0, b = h1;
        for (int off = 1; off < 64; off <<= 1) {
            unsigned int v = __shfl_up(a, off);
            if (t >= off) a += v;
        }
        const unsigned int atot = __shfl(a, 63);
        for (int off = 1; off < 64; off <<= 1) {
            unsigned int v = __shfl_up(b, off);
            if (t >= off) b += v;
        }
        rowstart[t]      = a - h0;
        rowstart[64 + t] = atot + b - h1;
        cursor[t]        = a - h0;
        cursor[64 + t]   = atot + b - h1;
        if (t == 63) rowstart[128] = atot + b;
    }
    __syncthreads();

    // d) counting-sort into LDS
    if (r0 >= 0) { const unsigned int p = atomicAdd(&cursor[r0], 1u); sorted[p] = e0s; }
    if (r1 >= 0) { const unsigned int p = atomicAdd(&cursor[r1], 1u); sorted[p] = e1s; }
    __syncthreads();

    // e) register accumulation, unroll-4 (4 outstanding gathers)
    const int wave = t >> 6;
    const int lane = t & 63;
    const int rbase = wave * 8;
    float acc[8];
    #pragma unroll
    for (int j = 0; j < 8; ++j) {
        unsigned int k = rowstart[rbase + j];
        const unsigned int ke = rowstart[rbase + j + 1];
        float a = 0.f;
        for (; k + 4 <= ke; k += 4) {
            const int2 e0 = sorted[k],     e1 = sorted[k + 1];
            const int2 e2 = sorted[k + 2], e3 = sorted[k + 3];
            const float x0 = X[((size_t)(e0.x & 0xFFFF) << 6) + lane];
            const float x1 = X[((size_t)(e1.x & 0xFFFF) << 6) + lane];
            const float x2 = X[((size_t)(e2.x & 0xFFFF) << 6) + lane];
            const float x3 = X[((size_t)(e3.x & 0xFFFF) << 6) + lane];
            a = fmaf(__int_as_float(e0.y), x0, a);
            a = fmaf(__int_as_float(e1.y), x1, a);
            a = fmaf(__int_as_float(e2.y), x2, a);
            a = fmaf(__int_as_float(e3.y), x3, a);
        }
        for (; k < ke; ++k) {
            const int2 e = sorted[k];
            a = fmaf(__int_as_float(e.y), X[((size_t)(e.x & 0xFFFF) << 6) + lane], a);
        }
        acc[j] = a;
    }

    // fold spill entries (expected none); static acc indexing (rule #20)
    if (s_nsp) {
        const int seglo = bkt * ROWS_PER_BKT;
        for (unsigned int k = 0; k < s_nsp; ++k) {
            const int2 e = spill[k];
            const int r = ((e.x >> 16) & 0xFFFF) - seglo;
            if (r >= rbase && r < rbase + 8) {
                const float xv = X[((size_t)(e.x & 0xFFFF) << 6) + lane];
                const float vv = __int_as_float(e.y);
                #pragma unroll
                for (int j = 0; j < 8; ++j)
                    if (r == rbase + j) acc[j] = fmaf(vv, xv, acc[j]);
            }
        }
    }

    float* obase = out + ((size_t)bkt * ROWS_PER_BKT + rbase) * ND + lane;
    #pragma unroll
    for (int j = 0; j < 8; ++j) obase[(size_t)j * ND] = acc[j];
}

// ---------------------------------------------------------------------------
// Fallback: proven atomic scatter (unexpected shape or small ws), raw masks.
// ---------------------------------------------------------------------------
__global__ void coo_scatter_kernel(const int* __restrict__ Ab,
                                   const int* __restrict__ Ar,
                                   const int* __restrict__ Ac,
                                   const float* __restrict__ Av,
                                   const float* __restrict__ X,
                                   const void* __restrict__ Xm_raw,
                                   const void* __restrict__ Tm_raw,
                                   float* __restrict__ out, int nnz) {
    __shared__ int s_flag;
    const bool bytes = detect_bytes_block(Xm_raw, &s_flag);
    const int groups_per_block = blockDim.x >> 6;
    const int g0 = blockIdx.x * groups_per_block + (threadIdx.x >> 6);
    const int gstr = gridDim.x * groups_per_block;
    const int lane = threadIdx.x & 63;
    for (int e = g0; e < nnz; e += gstr) {
        const int b = Ab[e];
        const int r = Ar[e];
        if (!mask_at(Tm_raw, bytes, b * NN + r)) continue;
        const int c = Ac[e];
        if (!mask_at(Xm_raw, bytes, b * NN + c)) continue;
        const float v = Av[e];
        const float x = X[((size_t)(b * NN + c)) * ND + lane];
        atomicAdd(&out[((size_t)(b * NN + r)) * ND + lane], v * x);
    }
}

extern "C" void kernel_launch(void* const* d_in, const int* in_sizes, int n_in,
                              void* d_out, int out_size, void* d_ws, size_t ws_size,
                              hipStream_t stream) {
    const int*   Ab = (const int*)d_in[0];
    const int*   Ar = (const int*)d_in[1];
    const int*   Ac = (const int*)d_in[2];
    const float* Av = (const float*)d_in[3];
    const float* X  = (const float*)d_in[4];
    const void*  Xm_raw = d_in[5];
    const void*  Tm_raw = d_in[6];
    float* out = (float*)d_out;

    const int nnz   = in_sizes[0];
    const int nmask = in_sizes[5];   // B*N

    // Workspace layout (8B aligned): ~8.9 MB total
    unsigned char* w = (unsigned char*)d_ws;
    unsigned int* cnt       = (unsigned int*)w;  w += (size_t)NSLOT * CNT_STRIDE * 4;
    unsigned int* spill_cnt = (unsigned int*)w;  w += 16;
    int2*         buckets   = (int2*)w;          w += (size_t)NSLOT * SUBCAP * 8;
    int2*         spill     = (int2*)w;          w += (size_t)SPILLCAP * 8;
    const size_t needed = (size_t)(w - (unsigned char*)d_ws);

    // Fast path requires the known problem shape (16-bit xrow/seg packing,
    // sub-bucket capacity sized for nnz=2M at ~25% survival).
    if (ws_size < needed || nmask != NBKT * ROWS_PER_BKT || (nnz & 3) || nnz > (1 << 22)) {
        hipMemsetAsync(d_out, 0, (size_t)out_size * sizeof(float), stream);
        coo_scatter_kernel<<<16384, 256, 0, stream>>>(Ab, Ar, Ac, Av, X,
                                                      Xm_raw, Tm_raw, out, nnz);
        return;
    }

    // Zero padded counters + spill counter in one memset (ws re-poisoned 0xAA
    // before every timed launch). No out memset: accum writes every row.
    hipMemsetAsync(cnt, 0, (size_t)NSLOT * CNT_STRIDE * 4 + 16, stream);

    const int nq = nnz >> 2;                 // 524288 int4 groups
    bin_kernel<<<2048, 256, 0, stream>>>(Ab, Ar, Ac, Av, Xm_raw, Tm_raw,
                                         cnt, buckets, spill_cnt, spill, nq);
    accum_kernel<<<NBKT, 1024, 0, stream>>>(cnt, buckets, X, spill_cnt, spill, out);
}

// Round 16
// 149.604 us; speedup vs baseline: 1.8512x; 1.0019x over previous
//
#include <hip/hip_runtime.h>

// Problem constants (reference: B=8, N=8192, D=64, NNZ=2097152)
#define NB 8
#define NN 8192
#define ND 64

// Binning geometry: 512 buckets x 128 output rows; 16 sub-buckets each.
// Round-14 lesson: counter contention is NOT bin's bottleneck (SUB 4->16 =
// no change); testing mask-gather latency via bit-packed L1-resident masks.
// Round-12 lesson: no grid.sync fusion (cooperative barrier ~90us).
#define NBKT 512
#define ROWS_PER_BKT 128
#define SUB 16
#define NSLOT (NBKT * SUB)       // 8192
#define SUBCAP 128
#define BKT_CAP (SUB * SUBCAP)   // 2048 entries max per bucket
#define CNT_STRIDE 16            // 64B per counter
#define SPILLCAP 16384
#define NMASK (NB * NN)          // 65536
#define NWORDS (NMASK / 32)      // 2048 u32 words per bitmask (8 KB)

// Mask format detection (bool upload convention unknown: 1-byte vs int32).
__device__ __forceinline__ bool detect_bytes_block(const void* xm_raw,
                                                   int* s_flag) {
    if (threadIdx.x == 0) *s_flag = 0;
    __syncthreads();
    const unsigned int* w = (const unsigned int*)xm_raw;
    if (threadIdx.x < 256 && w[threadIdx.x] > 1u) atomicOr(s_flag, 1);
    __syncthreads();
    return *s_flag != 0;
}

__device__ __forceinline__ unsigned int mask_at(const void* m, bool bytes, int i) {
    return bytes ? (unsigned int)((const unsigned char*)m)[i]
                 : ((const unsigned int*)m)[i];
}

// ---------------------------------------------------------------------------
// Pass 0: prep. (a) zero padded counters + spill counter (absorbs the old
// memset dispatch), (b) bit-pack both masks via __ballot -> 8 KB tables that
// stay L1-resident during bin. 32 blocks x 256 threads; coalesced reads.
// ---------------------------------------------------------------------------
__global__ void prep_kernel(const void* __restrict__ xm_raw,
                            const void* __restrict__ tm_raw,
                            unsigned int* __restrict__ xbits,
                            unsigned int* __restrict__ tbits,
                            unsigned int* __restrict__ cnt,
                            unsigned int* __restrict__ spill_cnt) {
    __shared__ int s_flag;
    const bool bytes = detect_bytes_block(xm_raw, &s_flag);
    const int t = threadIdx.x;           // 0..255
    const int lane = t & 63;

    // (a) zero counters: 8192 slots * 16 words = 131072 words = 32768 uint4
    {
        const int gt = blockIdx.x * 256 + t;             // 0..8191
        uint4* c4 = (uint4*)cnt;
        #pragma unroll
        for (int i = 0; i < 4; ++i)
            c4[gt + i * 8192] = make_uint4(0u, 0u, 0u, 0u);
        if (gt == 0) *spill_cnt = 0u;
    }

    // (b) bit-pack: block b owns elements [b*2048, (b+1)*2048)
    const int base = blockIdx.x * 2048;
    for (int off = 0; off < 2048; off += 256) {
        const int idx = base + off + t;
        const unsigned int xv = mask_at(xm_raw, bytes, idx);
        const unsigned int tv = mask_at(tm_raw, bytes, idx);
        const unsigned long long xb = __ballot(xv != 0u);
        const unsigned long long tb = __ballot(tv != 0u);
        if ((lane & 31) == 0) {
            const unsigned int xw = (lane == 0) ? (unsigned int)xb
                                                : (unsigned int)(xb >> 32);
            const unsigned int tw = (lane == 0) ? (unsigned int)tb
                                                : (unsigned int)(tb >> 32);
            xbits[idx >> 5] = xw;
            tbits[idx >> 5] = tw;
        }
    }
}

// ---------------------------------------------------------------------------
// Pass 1: bin surviving edges into sub-buckets. int4-vectorized index reads;
// mask tests via L1-resident 8 KB bit tables (both words loaded up front for
// MLP). Entry = (xrow | row_in_bucket<<16, val_bits). Padded counters.
// ---------------------------------------------------------------------------
__global__ void bin_kernel(const int* __restrict__ Ab, const int* __restrict__ Ar,
                           const int* __restrict__ Ac, const float* __restrict__ Av,
                           const unsigned int* __restrict__ xbits,
                           const unsigned int* __restrict__ tbits,
                           unsigned int* __restrict__ cnt,
                           int2* __restrict__ buckets,
                           unsigned int* __restrict__ spill_cnt,
                           int2* __restrict__ spill,
                           int nq) {
    const int sub = blockIdx.x & (SUB - 1);
    const int4*   Ab4 = (const int4*)Ab;
    const int4*   Ar4 = (const int4*)Ar;
    const int4*   Ac4 = (const int4*)Ac;
    const float4* Av4 = (const float4*)Av;
    int i = blockIdx.x * blockDim.x + threadIdx.x;
    const int str = gridDim.x * blockDim.x;
    for (; i < nq; i += str) {
        const int4   b4 = Ab4[i];
        const int4   r4 = Ar4[i];
        const int4   c4 = Ac4[i];
        const float4 v4 = Av4[i];
        const int   bs[4] = {b4.x, b4.y, b4.z, b4.w};
        const int   rs[4] = {r4.x, r4.y, r4.z, r4.w};
        const int   cs[4] = {c4.x, c4.y, c4.z, c4.w};
        const float vs[4] = {v4.x, v4.y, v4.z, v4.w};

        int seg[4], xrow[4];
        unsigned int ok[4];
        #pragma unroll
        for (int j = 0; j < 4; ++j) {
            seg[j]  = bs[j] * NN + rs[j];
            xrow[j] = bs[j] * NN + cs[j];
            // both table loads issued unconditionally (L1-resident, MLP)
            const unsigned int tw = tbits[seg[j] >> 5];
            const unsigned int xw = xbits[xrow[j] >> 5];
            ok[j] = ((tw >> (seg[j] & 31)) & 1u) & ((xw >> (xrow[j] & 31)) & 1u);
        }
        #pragma unroll
        for (int j = 0; j < 4; ++j) {
            if (ok[j]) {
                const int slot = (seg[j] >> 7) * SUB + sub;
                const unsigned int pos = atomicAdd(&cnt[slot * CNT_STRIDE], 1u);
                if (pos < SUBCAP) {
                    buckets[(size_t)slot * SUBCAP + pos] =
                        make_int2(xrow[j] | ((seg[j] & (ROWS_PER_BKT - 1)) << 16),
                                  __float_as_int(vs[j]));
                } else {
                    const unsigned int sp = atomicAdd(spill_cnt, 1u);
                    if (sp < SPILLCAP)
                        spill[sp] = make_int2(xrow[j] | (seg[j] << 16),
                                              __float_as_int(vs[j]));
                }
            }
        }
    }
}

// ---------------------------------------------------------------------------
// Pass 2: one block (1024 thr) per bucket.
//   a) stage <=2048 entries  b) LDS u32 histogram by row  c) wave-0 shfl scan
//   d) counting-sort into LDS  e) wave w accumulates rows 8w..8w+7 in VGPRs,
//      unroll-4 for 4 outstanding X gathers, folds spill entries (expected 0),
//      writes 8 coalesced 256B rows. Writes every row -> no out memset.
// ---------------------------------------------------------------------------
__global__ __launch_bounds__(1024) void accum_kernel(const unsigned int* __restrict__ cnt,
                                                     const int2* __restrict__ buckets,
                                                     const float* __restrict__ X,
                                                     const unsigned int* __restrict__ spill_cnt,
                                                     const int2* __restrict__ spill,
                                                     float* __restrict__ out) {
    __shared__ int2 sorted[BKT_CAP];                   // 16 KB
    __shared__ unsigned int hist[ROWS_PER_BKT];
    __shared__ unsigned int rowstart[ROWS_PER_BKT + 1];
    __shared__ unsigned int cursor[ROWS_PER_BKT];
    __shared__ unsigned int s_n[SUB];
    __shared__ unsigned int s_nsp;

    const int bkt = blockIdx.x;
    const int t = threadIdx.x;

    if (t < ROWS_PER_BKT) hist[t] = 0;
    if (t < SUB) s_n[t] = min(cnt[(bkt * SUB + t) * CNT_STRIDE], (unsigned int)SUBCAP);
    if (t == 0) s_nsp = min(*spill_cnt, (unsigned int)SPILLCAP);
    __syncthreads();

    // a+b) stage + histogram (idx space: sub = idx/SUBCAP, off = idx%SUBCAP)
    int2 e0s, e1s;
    int r0 = -1, r1 = -1;
    {
        int idx = t, sub = idx >> 7, off = idx & (SUBCAP - 1);
        if ((unsigned int)off < s_n[sub]) {
            e0s = buckets[(size_t)(bkt * SUB + sub) * SUBCAP + off];
            r0 = (e0s.x >> 16) & (ROWS_PER_BKT - 1);
            atomicAdd(&hist[r0], 1u);
        }
        idx = t + 1024; sub = idx >> 7; off = idx & (SUBCAP - 1);
        if ((unsigned int)off < s_n[sub]) {
            e1s = buckets[(size_t)(bkt * SUB + sub) * SUBCAP + off];
            r1 = (e1s.x >> 16) & (ROWS_PER_BKT - 1);
            atomicAdd(&hist[r1], 1u);
        }
    }
    __syncthreads();

    // c) exclusive scan of 128 counts by wave 0
    if (t < 64) {
        const unsigned int h0 = hist[t], h1 = hist[64 + t];
        unsigned int a = h0, b = h1;
        for (int off = 1; off < 64; off <<= 1) {
            unsigned int v = __shfl_up(a, off);
            if (t >= off) a += v;
        }
        const unsigned int atot = __shfl(a, 63);
        for (int off = 1; off < 64; off <<= 1) {
            unsigned int v = __shfl_up(b, off);
            if (t >= off) b += v;
        }
        rowstart[t]      = a - h0;
        rowstart[64 + t] = atot + b - h1;
        cursor[t]        = a - h0;
        cursor[64 + t]   = atot + b - h1;
        if (t == 63) rowstart[128] = atot + b;
    }
    __syncthreads();

    // d) counting-sort into LDS
    if (r0 >= 0) { const unsigned int p = atomicAdd(&cursor[r0], 1u); sorted[p] = e0s; }
    if (r1 >= 0) { const unsigned int p = atomicAdd(&cursor[r1], 1u); sorted[p] = e1s; }
    __syncthreads();

    // e) register accumulation, unroll-4 (4 outstanding gathers)
    const int wave = t >> 6;
    const int lane = t & 63;
    const int rbase = wave * 8;
    float acc[8];
    #pragma unroll
    for (int j = 0; j < 8; ++j) {
        unsigned int k = rowstart[rbase + j];
        const unsigned int ke = rowstart[rbase + j + 1];
        float a = 0.f;
        for (; k + 4 <= ke; k += 4) {
            const int2 e0 = sorted[k],     e1 = sorted[k + 1];
            const int2 e2 = sorted[k + 2], e3 = sorted[k + 3];
            const float x0 = X[((size_t)(e0.x & 0xFFFF) << 6) + lane];
            const float x1 = X[((size_t)(e1.x & 0xFFFF) << 6) + lane];
            const float x2 = X[((size_t)(e2.x & 0xFFFF) << 6) + lane];
            const float x3 = X[((size_t)(e3.x & 0xFFFF) << 6) + lane];
            a = fmaf(__int_as_float(e0.y), x0, a);
            a = fmaf(__int_as_float(e1.y), x1, a);
            a = fmaf(__int_as_float(e2.y), x2, a);
            a = fmaf(__int_as_float(e3.y), x3, a);
        }
        for (; k < ke; ++k) {
            const int2 e = sorted[k];
            a = fmaf(__int_as_float(e.y), X[((size_t)(e.x & 0xFFFF) << 6) + lane], a);
        }
        acc[j] = a;
    }

    // fold spill entries (expected none); static acc indexing (rule #20)
    if (s_nsp) {
        const int seglo = bkt * ROWS_PER_BKT;
        for (unsigned int k = 0; k < s_nsp; ++k) {
            const int2 e = spill[k];
            const int r = ((e.x >> 16) & 0xFFFF) - seglo;
            if (r >= rbase && r < rbase + 8) {
                const float xv = X[((size_t)(e.x & 0xFFFF) << 6) + lane];
                const float vv = __int_as_float(e.y);
                #pragma unroll
                for (int j = 0; j < 8; ++j)
                    if (r == rbase + j) acc[j] = fmaf(vv, xv, acc[j]);
            }
        }
    }

    float* obase = out + ((size_t)bkt * ROWS_PER_BKT + rbase) * ND + lane;
    #pragma unroll
    for (int j = 0; j < 8; ++j) obase[(size_t)j * ND] = acc[j];
}

// ---------------------------------------------------------------------------
// Fallback: proven atomic scatter (unexpected shape or small ws), raw masks.
// ---------------------------------------------------------------------------
__global__ void coo_scatter_kernel(const int* __restrict__ Ab,
                                   const int* __restrict__ Ar,
                                   const int* __restrict__ Ac,
                                   const float* __restrict__ Av,
                                   const float* __restrict__ X,
                                   const void* __restrict__ Xm_raw,
                                   const void* __restrict__ Tm_raw,
                                   float* __restrict__ out, int nnz) {
    __shared__ int s_flag;
    const bool bytes = detect_bytes_block(Xm_raw, &s_flag);
    const int groups_per_block = blockDim.x >> 6;
    const int g0 = blockIdx.x * groups_per_block + (threadIdx.x >> 6);
    const int gstr = gridDim.x * groups_per_block;
    const int lane = threadIdx.x & 63;
    for (int e = g0; e < nnz; e += gstr) {
        const int b = Ab[e];
        const int r = Ar[e];
        if (!mask_at(Tm_raw, bytes, b * NN + r)) continue;
        const int c = Ac[e];
        if (!mask_at(Xm_raw, bytes, b * NN + c)) continue;
        const float v = Av[e];
        const float x = X[((size_t)(b * NN + c)) * ND + lane];
        atomicAdd(&out[((size_t)(b * NN + r)) * ND + lane], v * x);
    }
}

extern "C" void kernel_launch(void* const* d_in, const int* in_sizes, int n_in,
                              void* d_out, int out_size, void* d_ws, size_t ws_size,
                              hipStream_t stream) {
    const int*   Ab = (const int*)d_in[0];
    const int*   Ar = (const int*)d_in[1];
    const int*   Ac = (const int*)d_in[2];
    const float* Av = (const float*)d_in[3];
    const float* X  = (const float*)d_in[4];
    const void*  Xm_raw = d_in[5];
    const void*  Tm_raw = d_in[6];
    float* out = (float*)d_out;

    const int nnz   = in_sizes[0];
    const int nmask = in_sizes[5];   // B*N

    // Workspace layout (8B aligned): ~8.9 MB total
    unsigned char* w = (unsigned char*)d_ws;
    unsigned int* cnt       = (unsigned int*)w;  w += (size_t)NSLOT * CNT_STRIDE * 4;
    unsigned int* spill_cnt = (unsigned int*)w;  w += 16;
    unsigned int* xbits     = (unsigned int*)w;  w += (size_t)NWORDS * 4;
    unsigned int* tbits     = (unsigned int*)w;  w += (size_t)NWORDS * 4;
    int2*         buckets   = (int2*)w;          w += (size_t)NSLOT * SUBCAP * 8;
    int2*         spill     = (int2*)w;          w += (size_t)SPILLCAP * 8;
    const size_t needed = (size_t)(w - (unsigned char*)d_ws);

    // Fast path requires the known problem shape (16-bit xrow/seg packing,
    // sub-bucket capacity sized for nnz=2M at ~25% survival).
    if (ws_size < needed || nmask != NMASK || (nnz & 3) || nnz > (1 << 22)) {
        hipMemsetAsync(d_out, 0, (size_t)out_size * sizeof(float), stream);
        coo_scatter_kernel<<<16384, 256, 0, stream>>>(Ab, Ar, Ac, Av, X,
                                                      Xm_raw, Tm_raw, out, nnz);
        return;
    }

    // 3 dispatches: prep (zero counters + bitpack masks), bin, accum.
    // No out memset: accum writes every output row.
    prep_kernel<<<32, 256, 0, stream>>>(Xm_raw, Tm_raw, xbits, tbits,
                                        cnt, spill_cnt);
    const int nq = nnz >> 2;                 // 524288 int4 groups
    bin_kernel<<<2048, 256, 0, stream>>>(Ab, Ar, Ac, Av, xbits, tbits,
                                         cnt, buckets, spill_cnt, spill, nq);
    accum_kernel<<<NBKT, 1024, 0, stream>>>(cnt, buckets, X, spill_cnt, spill, out);
}